// Round 4
// baseline (179.623 us; speedup 1.0000x reference)
//
#include <hip/hip_runtime.h>
#include <hip/hip_bf16.h>

typedef __attribute__((ext_vector_type(8))) short short8;
typedef __attribute__((ext_vector_type(16))) float floatx16;
typedef __attribute__((ext_vector_type(4))) float floatx4;
typedef __attribute__((ext_vector_type(4))) unsigned uintx4;

__device__ __forceinline__ short f2bf(float f) {
    unsigned u = __builtin_bit_cast(unsigned, f);
    u += 0x7fffu + ((u >> 16) & 1u);   // RNE
    return (short)(u >> 16);
}

__device__ __forceinline__ unsigned pk_bf16(float lo, float hi) {
    unsigned short a = __builtin_bit_cast(unsigned short, (__bf16)lo);
    unsigned short b = __builtin_bit_cast(unsigned short, (__bf16)hi);
    return (unsigned)a | ((unsigned)b << 16);
}

__device__ __forceinline__ void gload_lds16(const void* g, void* l) {
    __builtin_amdgcn_global_load_lds(
        (const __attribute__((address_space(1))) unsigned*)g,
        (__attribute__((address_space(3))) unsigned*)l, 16, 0, 0);
}

// ---------------------------------------------------------------------------
// f32 -> bf16 convert with GEMM LDS swizzle baked into global layout.
__global__ __launch_bounds__(256)
void convsw(const float* __restrict__ src, short* __restrict__ dst) {
    const int row = blockIdx.x;
    const int c = threadIdx.x;
    const int kt = c >> 2, cc = c & 3;
    const int cs = cc ^ ((row >> 1) & 3);
    const float* s = src + (size_t)row * 2048 + kt * 32 + cs * 8;
    float4 v0 = *(const float4*)s;
    float4 v1 = *(const float4*)(s + 4);
    short8 o = { f2bf(v0.x), f2bf(v0.y), f2bf(v0.z), f2bf(v0.w),
                 f2bf(v1.x), f2bf(v1.y), f2bf(v1.z), f2bf(v1.w) };
    *(short8*)(dst + (size_t)row * 2048 + kt * 32 + cc * 8) = o;
}

__global__ __launch_bounds__(256)
void convsw_qkv(const float* __restrict__ Wq, const float* __restrict__ Wk,
                const float* __restrict__ Wv, short* __restrict__ dst) {
    const int row = blockIdx.x;            // 0..3071
    const float* src; int srow;
    if (row < 2048)      { src = Wq; srow = row; }
    else if (row < 2560) { src = Wk; srow = row - 2048; }
    else                 { src = Wv; srow = row - 2560; }
    const int c = threadIdx.x;
    const int kt = c >> 2, cc = c & 3;
    const int cs = cc ^ ((row >> 1) & 3);
    const float* s = src + (size_t)srow * 2048 + kt * 32 + cs * 8;
    float4 v0 = *(const float4*)s;
    float4 v1 = *(const float4*)(s + 4);
    short8 o = { f2bf(v0.x), f2bf(v0.y), f2bf(v0.z), f2bf(v0.w),
                 f2bf(v1.x), f2bf(v1.y), f2bf(v1.z), f2bf(v1.w) };
    *(short8*)(dst + (size_t)row * 2048 + kt * 32 + cc * 8) = o;
}

// ---------------------------------------------------------------------------
// m97-style bf16 GEMM (unchanged). qb pre-scaled by 0.125*log2e.
template<int EPI>
__global__ __launch_bounds__(256)
void gemm_sw(const short* __restrict__ A, const short* __restrict__ Bw,
             short* __restrict__ qb, short* __restrict__ kb, short* __restrict__ vt,
             float* __restrict__ fout, const float* __restrict__ bias) {
    __shared__ short As[128 * 32];
    __shared__ short Bs[128 * 32];
    constexpr int K = 2048;
    const int t = threadIdx.x, lane = t & 63, w = t >> 6;
    const int wm = w >> 1, wn = w & 1;
    const int l15 = lane & 15, lh = lane >> 4;
    const int bn = blockIdx.x, bm = blockIdx.y;
    const int ra0 = bm * 128;
    const short* Bbase = Bw + (size_t)bn * 128 * K;
    const int pr = t >> 2, pc = t & 3;

    floatx4 acc[4][4] = {};

    for (int k0 = 0; k0 < K; k0 += 32) {
        #pragma unroll
        for (int i = 0; i < 2; ++i) {
            int row = i * 64 + pr;
            gload_lds16(A + (size_t)(ra0 + row) * K + k0 + pc * 8, As + (i * 256 + t) * 8);
            gload_lds16(Bbase + (size_t)row * K + k0 + pc * 8, Bs + (i * 256 + t) * 8);
        }
        __syncthreads();
        short8 a[4], b[4];
        #pragma unroll
        for (int m = 0; m < 4; ++m) {
            int row = wm * 64 + m * 16 + l15;
            a[m] = *(const short8*)(As + row * 32 + ((lh ^ ((row >> 1) & 3)) << 3));
        }
        #pragma unroll
        for (int n = 0; n < 4; ++n) {
            int row = wn * 64 + n * 16 + l15;
            b[n] = *(const short8*)(Bs + row * 32 + ((lh ^ ((row >> 1) & 3)) << 3));
        }
        #pragma unroll
        for (int m = 0; m < 4; ++m)
            #pragma unroll
            for (int n = 0; n < 4; ++n)
                acc[m][n] = __builtin_amdgcn_mfma_f32_16x16x32_bf16(a[m], b[n], acc[m][n], 0, 0, 0);
        __syncthreads();
    }

    #pragma unroll
    for (int m = 0; m < 4; ++m) {
        #pragma unroll
        for (int n = 0; n < 4; ++n) {
            #pragma unroll
            for (int r = 0; r < 4; ++r) {
                int row = ra0 + wm * 64 + m * 16 + lh * 4 + r;
                int col = bn * 128 + wn * 64 + n * 16 + l15;
                float v = acc[m][n][r];
                if constexpr (EPI == 1) {
                    fout[(size_t)row * 2048 + col] = v + bias[col];
                } else {
                    if (col < 2048) {
                        qb[(size_t)row * 2048 + col] = f2bf(v * 0.18033688011112042f);
                    } else if (col < 2560) {
                        int kcol = col - 2048, within = kcol & 63;
                        int cp = ((within >> 3) ^ (row & 7)) & 7;
                        kb[(size_t)row * 512 + (kcol & ~63) + (cp << 3) + (within & 7)] = f2bf(v);
                    } else {
                        int dg = col - 2560;
                        int cp = (((row >> 3) & 7) ^ (dg & 7)) & 7;
                        vt[(size_t)dg * 2048 + (row & ~63) + (cp << 3) + (row & 7)] = f2bf(v);
                    }
                }
            }
        }
    }
}

// ---------------------------------------------------------------------------
// Causal GQA attention, 32x32 MFMA, in-register softmax, KV-parity split.
// Block = 4 waves: wave = (strip s = w&1 of 32 q-rows, kv-parity p = w>>1).
// Per 128-row KV slab: K[128][64] + V^T[64][128] staged once; parity-p wave
// computes kv tile 2*ss+p. Partials merged per-strip via LDS at the end
// (lane = q column -> merge is per-lane scalar math).
__global__ __launch_bounds__(256)
void attn_fwd(const short* __restrict__ qb, const short* __restrict__ kb,
              const short* __restrict__ vt, short* __restrict__ ob) {
    __shared__ __align__(16) char smem[32768];
    short* Ks = (short*)smem;              // 128 kv-rows x 64 shorts (16 KB)
    short* Vs = (short*)(smem + 16384);    // 64 d-rows x 128 shorts (16 KB)
    float* Ms = (float*)smem;              // merge buffer (17 KB, reuses slab)

    const int t = threadIdx.x, lane = t & 63, w = t >> 6;
    const int l31 = lane & 31, hi = lane >> 5;
    const int qt = 31 - blockIdx.x;        // big tiles dispatch first
    const int hq = blockIdx.y, hk = hq >> 2;
    const int s = w & 1, p = w >> 1;
    const int q0 = qt * 64 + s * 32;
    const int rg = q0 + l31;               // this lane's q row
    const int swl = l31 & 7;

    short8 qf[4];
    {
        const short* qrow = qb + (size_t)rg * 2048 + hq * 64;
        #pragma unroll
        for (int kk = 0; kk < 4; ++kk)
            qf[kk] = *(const short8*)(qrow + kk * 16 + hi * 8);
    }

    float m = -3e38f, l = 0.f;
    floatx16 acc[2] = {};

    const int nss = (qt >> 1) + 1;
    for (int ss = 0; ss < nss; ++ss) {
        const int j0 = ss * 128;
        // ---- stage slab: K chunks 0..1023, V chunks 1024..2047 (16B each)
        #pragma unroll
        for (int i = 0; i < 8; ++i) {
            int c = i * 256 + t;
            if (i < 4) {
                int row = c >> 3, cc = c & 7;
                gload_lds16(kb + (size_t)(j0 + row) * 512 + hk * 64 + cc * 8, Ks + c * 8);
            } else {
                int cv = c - 1024, drow = cv >> 4, cc = cv & 15;
                gload_lds16(vt + (size_t)(hk * 64 + drow) * 2048 + j0 + cc * 8, Vs + cv * 8);
            }
        }
        __syncthreads();

        const int kt = 2 * ss + p;
        if (kt <= qt) {
            // ---- S^T = K . Q^T  (2 kv-blocks x 4 k-steps)
            floatx16 sT[2];
            #pragma unroll
            for (int kb2 = 0; kb2 < 2; ++kb2) {
                floatx16 a = {};
                const int row = p * 64 + kb2 * 32 + l31;
                #pragma unroll
                for (int kk = 0; kk < 4; ++kk) {
                    short8 kf = *(const short8*)(Ks + row * 64 + (((2 * kk + hi) ^ swl) << 3));
                    a = __builtin_amdgcn_mfma_f32_32x32x16_bf16(kf, qf[kk], a, 0, 0, 0);
                }
                sT[kb2] = a;
            }

            // ---- causal mask (diagonal tile only)
            if (kt == qt) {
                #pragma unroll
                for (int kb2 = 0; kb2 < 2; ++kb2)
                    #pragma unroll
                    for (int r = 0; r < 16; ++r) {
                        int jg = kt * 64 + kb2 * 32 + (r & 3) + 8 * (r >> 2) + 4 * hi;
                        if (jg > rg) sT[kb2][r] = -3e38f;
                    }
            }

            // ---- row max (in-lane tree + 1 cross-half exchange)
            float v[16];
            #pragma unroll
            for (int r = 0; r < 16; ++r) v[r] = fmaxf(sT[0][r], sT[1][r]);
            #pragma unroll
            for (int st = 8; st >= 1; st >>= 1)
                #pragma unroll
                for (int r = 0; r < 8; ++r)
                    if (r < st) v[r] = fmaxf(v[r], v[r + st]);
            float tm = fmaxf(v[0], __shfl_xor(v[0], 32));

            // ---- defer-max
            if (!__all(tm <= m + 8.0f)) {
                float mn = fmaxf(m, tm);
                float sf = __builtin_amdgcn_exp2f(m - mn);
                m = mn;
                l *= sf;
                #pragma unroll
                for (int n = 0; n < 2; ++n)
                    #pragma unroll
                    for (int r = 0; r < 16; ++r) acc[n][r] *= sf;
            }

            // ---- p = exp2(s - m), row sum
            float sv[16];
            #pragma unroll
            for (int kb2 = 0; kb2 < 2; ++kb2)
                #pragma unroll
                for (int r = 0; r < 16; ++r)
                    sT[kb2][r] = __builtin_amdgcn_exp2f(sT[kb2][r] - m);
            #pragma unroll
            for (int r = 0; r < 16; ++r) sv[r] = sT[0][r] + sT[1][r];
            #pragma unroll
            for (int st = 8; st >= 1; st >>= 1)
                #pragma unroll
                for (int r = 0; r < 8; ++r)
                    if (r < st) sv[r] += sv[r + st];
            l += sv[0] + __shfl_xor(sv[0], 32);

            // ---- P^T -> B-fragments (cvt_pk + cross-half exchange), then PV
            #pragma unroll
            for (int kb2 = 0; kb2 < 2; ++kb2) {
                unsigned Qd[8], Pd[8];
                #pragma unroll
                for (int c = 0; c < 8; ++c)
                    Qd[c] = pk_bf16(sT[kb2][2 * c], sT[kb2][2 * c + 1]);
                #pragma unroll
                for (int c = 0; c < 8; ++c)
                    Pd[c] = __shfl_xor(Qd[c], 32);
                #pragma unroll
                for (int b = 0; b < 2; ++b) {
                    uintx4 j;
                    if (b == 0) {
                        j.x = hi ? Pd[2] : Qd[0];
                        j.y = hi ? Pd[3] : Qd[1];
                        j.z = hi ? Qd[2] : Pd[0];
                        j.w = hi ? Qd[3] : Pd[1];
                    } else {
                        j.x = hi ? Pd[6] : Qd[4];
                        j.y = hi ? Pd[7] : Qd[5];
                        j.z = hi ? Qd[6] : Pd[4];
                        j.w = hi ? Qd[7] : Pd[5];
                    }
                    short8 pf = __builtin_bit_cast(short8, j);
                    const int kk = kb2 * 2 + b;
                    const int ch = p * 64 + (((2 * kk + hi) ^ swl) << 3);
                    short8 vf0 = *(const short8*)(Vs + l31 * 128 + ch);
                    acc[0] = __builtin_amdgcn_mfma_f32_32x32x16_bf16(vf0, pf, acc[0], 0, 0, 0);
                    short8 vf1 = *(const short8*)(Vs + (32 + l31) * 128 + ch);
                    acc[1] = __builtin_amdgcn_mfma_f32_32x32x16_bf16(vf1, pf, acc[1], 0, 0, 0);
                }
            }
        }
        __syncthreads();   // protect slab before next stage / merge
    }

    // ---- merge the two kv-parity partials per strip (lane = q column)
    float* mb = Ms + ((size_t)s * 64 + lane) * 34;
    if (p == 1) {
        #pragma unroll
        for (int n = 0; n < 2; ++n)
            #pragma unroll
            for (int r = 0; r < 16; ++r) mb[n * 16 + r] = acc[n][r];
        mb[32] = m;
        mb[33] = l;
    }
    __syncthreads();
    if (p == 0) {
        const float m1 = mb[32], l1 = mb[33];
        const float M = fmaxf(m, m1);
        const float sf0 = __builtin_amdgcn_exp2f(m - M);
        const float sf1 = __builtin_amdgcn_exp2f(m1 - M);
        const float linv = 1.0f / (sf0 * l + sf1 * l1);
        const int sw = (rg >> 1) & 3;
        #pragma unroll
        for (int n = 0; n < 2; ++n) {
            #pragma unroll
            for (int g = 0; g < 4; ++g) {
                #pragma unroll
                for (int e = 0; e < 4; e += 2) {
                    int r = 4 * g + e;
                    float o0 = (sf0 * acc[n][r]     + sf1 * mb[n * 16 + r])     * linv;
                    float o1 = (sf0 * acc[n][r + 1] + sf1 * mb[n * 16 + r + 1]) * linv;
                    unsigned pkv = pk_bf16(o0, o1);
                    int d = 32 * n + e + 8 * g + 4 * hi;
                    int col = hq * 64 + d;
                    int cp = ((col >> 3) & 3) ^ sw;
                    *(unsigned*)(ob + (size_t)rg * 2048 + (col & ~31) + (cp << 3) + (col & 7)) = pkv;
                }
            }
        }
    }
}

// ---------------------------------------------------------------------------
extern "C" void kernel_launch(void* const* d_in, const int* in_sizes, int n_in,
                              void* d_out, int out_size, void* d_ws, size_t ws_size,
                              hipStream_t stream) {
    const float* x  = (const float*)d_in[0];
    const float* Wq = (const float*)d_in[1];
    const float* Wk = (const float*)d_in[2];
    const float* Wv = (const float*)d_in[3];
    const float* Wo = (const float*)d_in[4];
    const float* bo = (const float*)d_in[5];

    char* ws = (char*)d_ws;
    short* xb   = (short*)ws;                            // 8 MiB (reused as ob)
    short* wqkv = (short*)(ws + ((size_t)8  << 20));     // 12 MiB (reused as wob)
    short* qb   = (short*)(ws + ((size_t)20 << 20));     // 8 MiB
    short* kb   = (short*)(ws + ((size_t)28 << 20));     // 2 MiB (attn-swizzled)
    short* vt   = (short*)(ws + ((size_t)30 << 20));     // 2 MiB (V^T, attn-swizzled)
    short* ob   = xb;      // x dead after QKV GEMM
    short* wob  = wqkv;    // qkv weights dead after QKV GEMM

    convsw<<<2048, 256, 0, stream>>>(x, xb);
    convsw_qkv<<<3072, 256, 0, stream>>>(Wq, Wk, Wv, wqkv);
    gemm_sw<0><<<dim3(24, 16), 256, 0, stream>>>(xb, wqkv, qb, kb, vt, nullptr, nullptr);
    convsw<<<2048, 256, 0, stream>>>(Wo, wob);
    attn_fwd<<<dim3(32, 32), 256, 0, stream>>>(qb, kb, vt, ob);
    gemm_sw<1><<<dim3(16, 16), 256, 0, stream>>>(ob, wob, nullptr, nullptr, nullptr,
                                                 (float*)d_out, bo);
}

// Round 5
// 147.109 us; speedup vs baseline: 1.2210x; 1.2210x over previous
//
#include <hip/hip_runtime.h>
#include <hip/hip_bf16.h>

typedef __attribute__((ext_vector_type(8))) short short8;
typedef __attribute__((ext_vector_type(16))) float floatx16;
typedef __attribute__((ext_vector_type(4))) float floatx4;
typedef __attribute__((ext_vector_type(4))) unsigned uintx4;

__device__ __forceinline__ short f2bf(float f) {
    unsigned u = __builtin_bit_cast(unsigned, f);
    u += 0x7fffu + ((u >> 16) & 1u);   // RNE
    return (short)(u >> 16);
}

__device__ __forceinline__ unsigned pk_bf16(float lo, float hi) {
    unsigned short a = __builtin_bit_cast(unsigned short, (__bf16)lo);
    unsigned short b = __builtin_bit_cast(unsigned short, (__bf16)hi);
    return (unsigned)a | ((unsigned)b << 16);
}

__device__ __forceinline__ void gload_lds16(const void* g, void* l) {
    __builtin_amdgcn_global_load_lds(
        (const __attribute__((address_space(1))) unsigned*)g,
        (__attribute__((address_space(3))) unsigned*)l, 16, 0, 0);
}

// ---------------------------------------------------------------------------
// f32 -> bf16 convert with GEMM LDS swizzle baked into global layout.
__global__ __launch_bounds__(256)
void convsw(const float* __restrict__ src, short* __restrict__ dst) {
    const int row = blockIdx.x;
    const int c = threadIdx.x;
    const int kt = c >> 2, cc = c & 3;
    const int cs = cc ^ ((row >> 1) & 3);
    const float* s = src + (size_t)row * 2048 + kt * 32 + cs * 8;
    float4 v0 = *(const float4*)s;
    float4 v1 = *(const float4*)(s + 4);
    short8 o = { f2bf(v0.x), f2bf(v0.y), f2bf(v0.z), f2bf(v0.w),
                 f2bf(v1.x), f2bf(v1.y), f2bf(v1.z), f2bf(v1.w) };
    *(short8*)(dst + (size_t)row * 2048 + kt * 32 + cc * 8) = o;
}

__global__ __launch_bounds__(256)
void convsw_qkv(const float* __restrict__ Wq, const float* __restrict__ Wk,
                const float* __restrict__ Wv, short* __restrict__ dst) {
    const int row = blockIdx.x;            // 0..3071
    const float* src; int srow;
    if (row < 2048)      { src = Wq; srow = row; }
    else if (row < 2560) { src = Wk; srow = row - 2048; }
    else                 { src = Wv; srow = row - 2560; }
    const int c = threadIdx.x;
    const int kt = c >> 2, cc = c & 3;
    const int cs = cc ^ ((row >> 1) & 3);
    const float* s = src + (size_t)srow * 2048 + kt * 32 + cs * 8;
    float4 v0 = *(const float4*)s;
    float4 v1 = *(const float4*)(s + 4);
    short8 o = { f2bf(v0.x), f2bf(v0.y), f2bf(v0.z), f2bf(v0.w),
                 f2bf(v1.x), f2bf(v1.y), f2bf(v1.z), f2bf(v1.w) };
    *(short8*)(dst + (size_t)row * 2048 + kt * 32 + cc * 8) = o;
}

// ---------------------------------------------------------------------------
// m97-style bf16 GEMM (unchanged). qb pre-scaled by 0.125*log2e.
template<int EPI>
__global__ __launch_bounds__(256)
void gemm_sw(const short* __restrict__ A, const short* __restrict__ Bw,
             short* __restrict__ qb, short* __restrict__ kb, short* __restrict__ vt,
             float* __restrict__ fout, const float* __restrict__ bias) {
    __shared__ short As[128 * 32];
    __shared__ short Bs[128 * 32];
    constexpr int K = 2048;
    const int t = threadIdx.x, lane = t & 63, w = t >> 6;
    const int wm = w >> 1, wn = w & 1;
    const int l15 = lane & 15, lh = lane >> 4;
    const int bn = blockIdx.x, bm = blockIdx.y;
    const int ra0 = bm * 128;
    const short* Bbase = Bw + (size_t)bn * 128 * K;
    const int pr = t >> 2, pc = t & 3;

    floatx4 acc[4][4] = {};

    for (int k0 = 0; k0 < K; k0 += 32) {
        #pragma unroll
        for (int i = 0; i < 2; ++i) {
            int row = i * 64 + pr;
            gload_lds16(A + (size_t)(ra0 + row) * K + k0 + pc * 8, As + (i * 256 + t) * 8);
            gload_lds16(Bbase + (size_t)row * K + k0 + pc * 8, Bs + (i * 256 + t) * 8);
        }
        __syncthreads();
        short8 a[4], b[4];
        #pragma unroll
        for (int m = 0; m < 4; ++m) {
            int row = wm * 64 + m * 16 + l15;
            a[m] = *(const short8*)(As + row * 32 + ((lh ^ ((row >> 1) & 3)) << 3));
        }
        #pragma unroll
        for (int n = 0; n < 4; ++n) {
            int row = wn * 64 + n * 16 + l15;
            b[n] = *(const short8*)(Bs + row * 32 + ((lh ^ ((row >> 1) & 3)) << 3));
        }
        #pragma unroll
        for (int m = 0; m < 4; ++m)
            #pragma unroll
            for (int n = 0; n < 4; ++n)
                acc[m][n] = __builtin_amdgcn_mfma_f32_16x16x32_bf16(a[m], b[n], acc[m][n], 0, 0, 0);
        __syncthreads();
    }

    #pragma unroll
    for (int m = 0; m < 4; ++m) {
        #pragma unroll
        for (int n = 0; n < 4; ++n) {
            #pragma unroll
            for (int r = 0; r < 4; ++r) {
                int row = ra0 + wm * 64 + m * 16 + lh * 4 + r;
                int col = bn * 128 + wn * 64 + n * 16 + l15;
                float v = acc[m][n][r];
                if constexpr (EPI == 1) {
                    fout[(size_t)row * 2048 + col] = v + bias[col];
                } else {
                    if (col < 2048) {
                        qb[(size_t)row * 2048 + col] = f2bf(v * 0.18033688011112042f);
                    } else if (col < 2560) {
                        int kcol = col - 2048, within = kcol & 63;
                        int cp = ((within >> 3) ^ (row & 7)) & 7;
                        kb[(size_t)row * 512 + (kcol & ~63) + (cp << 3) + (within & 7)] = f2bf(v);
                    } else {
                        int dg = col - 2560;
                        int cp = (((row >> 3) & 7) ^ (dg & 7)) & 7;
                        vt[(size_t)dg * 2048 + (row & ~63) + (cp << 3) + (row & 7)] = f2bf(v);
                    }
                }
            }
        }
    }
}

// ---------------------------------------------------------------------------
// Causal GQA attention: 8 waves = 4 q-strips {A0,A1,B0,B1} x kv-parity.
// Pair {i, 31-i} per block (uniform work); 128-kv-row slabs double-buffered;
// one barrier per slab; parity partials merged per-strip via LDS.
__global__ __launch_bounds__(512, 4)
void attn_fwd(const short* __restrict__ qb, const short* __restrict__ kb,
              const short* __restrict__ vt, short* __restrict__ ob) {
    __shared__ __align__(16) short smem[2][16384];  // per buf: K 128x64 | V^T 64x128 (32 KB)

    const int t = threadIdx.x, lane = t & 63, w = t >> 6;
    const int l31 = lane & 31, hi = lane >> 5;
    const int pairi = blockIdx.x;              // 0..15
    const int hq = blockIdx.y, hk = hq >> 2;
    const int qtA = pairi, qtB = 31 - pairi;
    const int a = w >> 1, p = w & 1;           // strip 0..3, kv parity
    const int myqt = (a < 2) ? qtA : qtB;
    const int q0 = myqt * 64 + (a & 1) * 32;
    const int rg = q0 + l31;                   // this lane's q row
    const int swl = l31 & 7;

    short8 qf[4];
    {
        const short* qrow = qb + (size_t)rg * 2048 + hq * 64;
        #pragma unroll
        for (int kk = 0; kk < 4; ++kk)
            qf[kk] = *(const short8*)(qrow + kk * 16 + hi * 8);
    }

    float m = -3e38f, l = 0.f;
    floatx16 acc[2] = {};

    auto stage = [&](int buf, int j0) {
        short* base = &smem[buf][0];
        #pragma unroll
        for (int i = 0; i < 4; ++i) {
            int c = i * 512 + t;
            if (i < 2) {                       // K chunks 0..1023
                int row = c >> 3, cc = c & 7;
                gload_lds16(kb + (size_t)(j0 + row) * 512 + hk * 64 + cc * 8, base + c * 8);
            } else {                           // V chunks 1024..2047
                int cv = c - 1024, drow = cv >> 4, cc = cv & 15;
                gload_lds16(vt + (size_t)(hk * 64 + drow) * 2048 + j0 + cc * 8, base + c * 8);
            }
        }
    };

    const int nss = (qtB >> 1) + 1;
    stage(0, 0);
    for (int ss = 0; ss < nss; ++ss) {
        __syncthreads();                       // slab ss ready (vm drained at barrier)
        if (ss + 1 < nss) stage((ss + 1) & 1, (ss + 1) * 128);
        const int kt = 2 * ss + p;
        if (kt <= myqt) {
            const short* K0 = &smem[ss & 1][0];
            const short* V0 = &smem[ss & 1][8192];

            // ---- S^T = K . Q^T  (2 kv-blocks x 4 k-steps)
            floatx16 sT[2];
            #pragma unroll
            for (int kb2 = 0; kb2 < 2; ++kb2) {
                floatx16 acc2 = {};
                const int row = p * 64 + kb2 * 32 + l31;
                #pragma unroll
                for (int kk = 0; kk < 4; ++kk) {
                    short8 kf = *(const short8*)(K0 + row * 64 + (((2 * kk + hi) ^ swl) << 3));
                    acc2 = __builtin_amdgcn_mfma_f32_32x32x16_bf16(kf, qf[kk], acc2, 0, 0, 0);
                }
                sT[kb2] = acc2;
            }

            // ---- causal mask (diagonal tile only)
            if (kt == myqt) {
                #pragma unroll
                for (int kb2 = 0; kb2 < 2; ++kb2)
                    #pragma unroll
                    for (int r = 0; r < 16; ++r) {
                        int jg = kt * 64 + kb2 * 32 + (r & 3) + 8 * (r >> 2) + 4 * hi;
                        if (jg > rg) sT[kb2][r] = -3e38f;
                    }
            }

            // ---- row max (in-lane tree + 1 cross-half exchange)
            float v[16];
            #pragma unroll
            for (int r = 0; r < 16; ++r) v[r] = fmaxf(sT[0][r], sT[1][r]);
            #pragma unroll
            for (int st = 8; st >= 1; st >>= 1)
                #pragma unroll
                for (int r = 0; r < 8; ++r)
                    if (r < st) v[r] = fmaxf(v[r], v[r + st]);
            float tm = fmaxf(v[0], __shfl_xor(v[0], 32));

            // ---- defer-max
            if (!__all(tm <= m + 8.0f)) {
                float mn = fmaxf(m, tm);
                float sf = __builtin_amdgcn_exp2f(m - mn);
                m = mn;
                l *= sf;
                #pragma unroll
                for (int n = 0; n < 2; ++n)
                    #pragma unroll
                    for (int r = 0; r < 16; ++r) acc[n][r] *= sf;
            }

            // ---- p = exp2(s - m), row sum
            float sv[16];
            #pragma unroll
            for (int kb2 = 0; kb2 < 2; ++kb2)
                #pragma unroll
                for (int r = 0; r < 16; ++r)
                    sT[kb2][r] = __builtin_amdgcn_exp2f(sT[kb2][r] - m);
            #pragma unroll
            for (int r = 0; r < 16; ++r) sv[r] = sT[0][r] + sT[1][r];
            #pragma unroll
            for (int st = 8; st >= 1; st >>= 1)
                #pragma unroll
                for (int r = 0; r < 8; ++r)
                    if (r < st) sv[r] += sv[r + st];
            l += sv[0] + __shfl_xor(sv[0], 32);

            // ---- P^T -> B-fragments (cvt_pk + cross-half exchange), then PV
            #pragma unroll
            for (int kb2 = 0; kb2 < 2; ++kb2) {
                unsigned Qd[8], Pd[8];
                #pragma unroll
                for (int c = 0; c < 8; ++c)
                    Qd[c] = pk_bf16(sT[kb2][2 * c], sT[kb2][2 * c + 1]);
                #pragma unroll
                for (int c = 0; c < 8; ++c)
                    Pd[c] = __shfl_xor(Qd[c], 32);
                #pragma unroll
                for (int b = 0; b < 2; ++b) {
                    uintx4 j;
                    if (b == 0) {
                        j.x = hi ? Pd[2] : Qd[0];
                        j.y = hi ? Pd[3] : Qd[1];
                        j.z = hi ? Qd[2] : Pd[0];
                        j.w = hi ? Qd[3] : Pd[1];
                    } else {
                        j.x = hi ? Pd[6] : Qd[4];
                        j.y = hi ? Pd[7] : Qd[5];
                        j.z = hi ? Qd[6] : Pd[4];
                        j.w = hi ? Qd[7] : Pd[5];
                    }
                    short8 pf = __builtin_bit_cast(short8, j);
                    const int kk = kb2 * 2 + b;
                    const int ch = p * 64 + (((2 * kk + hi) ^ swl) << 3);
                    short8 vf0 = *(const short8*)(V0 + l31 * 128 + ch);
                    acc[0] = __builtin_amdgcn_mfma_f32_32x32x16_bf16(vf0, pf, acc[0], 0, 0, 0);
                    short8 vf1 = *(const short8*)(V0 + (32 + l31) * 128 + ch);
                    acc[1] = __builtin_amdgcn_mfma_f32_32x32x16_bf16(vf1, pf, acc[1], 0, 0, 0);
                }
            }
        }
    }

    // ---- merge the two kv-parity partials per strip (lane = q column)
    __syncthreads();                           // all compute done; reuse smem
    float* mb = (float*)&smem[0][0] + ((size_t)a * 64 + lane) * 34;
    if (p == 1) {
        #pragma unroll
        for (int n = 0; n < 2; ++n)
            #pragma unroll
            for (int r = 0; r < 16; ++r) mb[n * 16 + r] = acc[n][r];
        mb[32] = m;
        mb[33] = l;
    }
    __syncthreads();
    if (p == 0) {
        const float m1 = mb[32], l1 = mb[33];
        const float M = fmaxf(m, m1);
        const float sf0 = __builtin_amdgcn_exp2f(m - M);
        const float sf1 = __builtin_amdgcn_exp2f(m1 - M);
        const float linv = 1.0f / (sf0 * l + sf1 * l1);
        const int sw = (rg >> 1) & 3;
        #pragma unroll
        for (int n = 0; n < 2; ++n) {
            #pragma unroll
            for (int g = 0; g < 4; ++g) {
                #pragma unroll
                for (int e = 0; e < 4; e += 2) {
                    int r = 4 * g + e;
                    float o0 = (sf0 * acc[n][r]     + sf1 * mb[n * 16 + r])     * linv;
                    float o1 = (sf0 * acc[n][r + 1] + sf1 * mb[n * 16 + r + 1]) * linv;
                    unsigned pkv = pk_bf16(o0, o1);
                    int d = 32 * n + e + 8 * g + 4 * hi;
                    int col = hq * 64 + d;
                    int cp = ((col >> 3) & 3) ^ sw;
                    *(unsigned*)(ob + (size_t)rg * 2048 + (col & ~31) + (cp << 3) + (col & 7)) = pkv;
                }
            }
        }
    }
}

// ---------------------------------------------------------------------------
extern "C" void kernel_launch(void* const* d_in, const int* in_sizes, int n_in,
                              void* d_out, int out_size, void* d_ws, size_t ws_size,
                              hipStream_t stream) {
    const float* x  = (const float*)d_in[0];
    const float* Wq = (const float*)d_in[1];
    const float* Wk = (const float*)d_in[2];
    const float* Wv = (const float*)d_in[3];
    const float* Wo = (const float*)d_in[4];
    const float* bo = (const float*)d_in[5];

    char* ws = (char*)d_ws;
    short* xb   = (short*)ws;                            // 8 MiB (reused as ob)
    short* wqkv = (short*)(ws + ((size_t)8  << 20));     // 12 MiB (reused as wob)
    short* qb   = (short*)(ws + ((size_t)20 << 20));     // 8 MiB
    short* kb   = (short*)(ws + ((size_t)28 << 20));     // 2 MiB (attn-swizzled)
    short* vt   = (short*)(ws + ((size_t)30 << 20));     // 2 MiB (V^T, attn-swizzled)
    short* ob   = xb;      // x dead after QKV GEMM
    short* wob  = wqkv;    // qkv weights dead after QKV GEMM

    convsw<<<2048, 256, 0, stream>>>(x, xb);
    convsw_qkv<<<3072, 256, 0, stream>>>(Wq, Wk, Wv, wqkv);
    gemm_sw<0><<<dim3(24, 16), 256, 0, stream>>>(xb, wqkv, qb, kb, vt, nullptr, nullptr);
    convsw<<<2048, 256, 0, stream>>>(Wo, wob);
    attn_fwd<<<dim3(16, 32), 512, 0, stream>>>(qb, kb, vt, ob);
    gemm_sw<1><<<dim3(16, 16), 256, 0, stream>>>(ob, wob, nullptr, nullptr, nullptr,
                                                 (float*)d_out, bo);
}

// Round 6
// 122.358 us; speedup vs baseline: 1.4680x; 1.2023x over previous
//
#include <hip/hip_runtime.h>
#include <hip/hip_bf16.h>

typedef __attribute__((ext_vector_type(8))) short short8;
typedef __attribute__((ext_vector_type(16))) float floatx16;
typedef __attribute__((ext_vector_type(4))) float floatx4;
typedef __attribute__((ext_vector_type(4))) unsigned uintx4;

__device__ __forceinline__ short f2bf(float f) {
    unsigned u = __builtin_bit_cast(unsigned, f);
    u += 0x7fffu + ((u >> 16) & 1u);   // RNE
    return (short)(u >> 16);
}

__device__ __forceinline__ unsigned pk_bf16(float lo, float hi) {
    unsigned short a = __builtin_bit_cast(unsigned short, (__bf16)lo);
    unsigned short b = __builtin_bit_cast(unsigned short, (__bf16)hi);
    return (unsigned)a | ((unsigned)b << 16);
}

__device__ __forceinline__ void gload_lds16(const void* g, void* l) {
    __builtin_amdgcn_global_load_lds(
        (const __attribute__((address_space(1))) unsigned*)g,
        (__attribute__((address_space(3))) unsigned*)l, 16, 0, 0);
}

// ---------------------------------------------------------------------------
// f32 -> bf16 convert, 64-col-tile XOR swizzle: 16B chunk cc of row holds
// source chunk cc ^ (row & 7). One block = one 2048-col row, 256 chunks.
__global__ __launch_bounds__(256)
void convsw(const float* __restrict__ src, short* __restrict__ dst) {
    const int row = blockIdx.x;
    const int c = threadIdx.x;
    const int kt = c >> 3, cc = c & 7;
    const float* s = src + (size_t)row * 2048 + kt * 64 + (cc ^ (row & 7)) * 8;
    float4 v0 = *(const float4*)s;
    float4 v1 = *(const float4*)(s + 4);
    short8 o = { f2bf(v0.x), f2bf(v0.y), f2bf(v0.z), f2bf(v0.w),
                 f2bf(v1.x), f2bf(v1.y), f2bf(v1.z), f2bf(v1.w) };
    *(short8*)(dst + (size_t)row * 2048 + kt * 64 + cc * 8) = o;
}

// x (2048 rows) -> xb, and Wq/Wk/Wv (3072 rows) -> wqkv, one launch.
__global__ __launch_bounds__(256)
void conv_all(const float* __restrict__ x, const float* __restrict__ Wq,
              const float* __restrict__ Wk, const float* __restrict__ Wv,
              short* __restrict__ xb, short* __restrict__ wqkv) {
    const int bid = blockIdx.x;                // 0..5119
    const float* src; short* dst; int srow, drow;
    if (bid < 2048)      { src = x;  dst = xb;   srow = bid;        drow = bid; }
    else {
        int r = bid - 2048;
        dst = wqkv; drow = r;
        if (r < 2048)      { src = Wq; srow = r; }
        else if (r < 2560) { src = Wk; srow = r - 2048; }
        else               { src = Wv; srow = r - 2560; }
    }
    const int c = threadIdx.x;
    const int kt = c >> 3, cc = c & 7;
    const float* s = src + (size_t)srow * 2048 + kt * 64 + (cc ^ (drow & 7)) * 8;
    float4 v0 = *(const float4*)s;
    float4 v1 = *(const float4*)(s + 4);
    short8 o = { f2bf(v0.x), f2bf(v0.y), f2bf(v0.z), f2bf(v0.w),
                 f2bf(v1.x), f2bf(v1.y), f2bf(v1.z), f2bf(v1.w) };
    *(short8*)(dst + (size_t)drow * 2048 + kt * 64 + cc * 8) = o;
}

// ---------------------------------------------------------------------------
// 8-wave double-buffered bf16 GEMM: C[m,n] = sum_k A[m,k]*B[n,k].
// BM=128, BK=64, BN in {128, 64}; wave-tile 32 x BN/2. A/B pre-swizzled in
// global (64-col tiles, chunk ^ (row&7)); LDS staged linearly via
// global_load_lds, ds_read applies the XOR. Prefetch slab i+1 under compute i.
// EPI 0: QKV epilogue (qb plain pre-scaled, kb/vt attn-swizzled). EPI 1: f32+bias.
template<int BN, int EPI>
__global__ __launch_bounds__(512, 4)
void gemm8(const short* __restrict__ A, const short* __restrict__ Bw,
           short* __restrict__ qb, short* __restrict__ kb, short* __restrict__ vt,
           float* __restrict__ fout, const float* __restrict__ bias) {
    constexpr int K = 2048;
    constexpr int NN = BN / 32;                // b-frags per wave per kf
    constexpr int ACH = 128 * 8;               // A chunks per slab
    constexpr int NCH = (128 + BN) * 8;        // total 16B chunks per slab
    __shared__ short sm[2][(128 + BN) * 64];

    const int t = threadIdx.x, lane = t & 63, w = t >> 6;
    const int wm = w & 3, wn = w >> 2;         // 4 row strips x 2 col strips
    const int l15 = lane & 15, lh = lane >> 4;
    const int bn = blockIdx.x, bm = blockIdx.y;
    const int ra0 = bm * 128;
    const short* Bbase = Bw + (size_t)bn * BN * K;

    floatx4 acc[2][NN] = {};

    auto stage = [&](int buf, int k0) {
        short* base = &sm[buf][0];
        #pragma unroll
        for (int i = 0; i < NCH / 512; ++i) {
            int c = i * 512 + t;
            if (c < ACH) {
                int row = c >> 3, cc = c & 7;
                gload_lds16(A + (size_t)(ra0 + row) * K + k0 + cc * 8, base + c * 8);
            } else {
                int c2 = c - ACH;
                int row = c2 >> 3, cc = c2 & 7;
                gload_lds16(Bbase + (size_t)row * K + k0 + cc * 8, base + (ACH + c2) * 8);
            }
        }
    };

    stage(0, 0);
    #pragma unroll 1
    for (int it = 0; it < K / 64; ++it) {
        __syncthreads();                       // slab `it` ready
        if (it + 1 < K / 64) stage((it + 1) & 1, (it + 1) * 64);
        const short* As = &sm[it & 1][0];
        const short* Bs = As + 128 * 64;
        #pragma unroll
        for (int kf = 0; kf < 2; ++kf) {
            short8 a[2], b[NN];
            #pragma unroll
            for (int m = 0; m < 2; ++m) {
                int arow = wm * 32 + m * 16 + l15;
                a[m] = *(const short8*)(As + arow * 64 + (((kf * 4 + lh) ^ (arow & 7)) << 3));
            }
            #pragma unroll
            for (int n = 0; n < NN; ++n) {
                int brow = wn * (BN / 2) + n * 16 + l15;
                b[n] = *(const short8*)(Bs + brow * 64 + (((kf * 4 + lh) ^ (brow & 7)) << 3));
            }
            #pragma unroll
            for (int m = 0; m < 2; ++m)
                #pragma unroll
                for (int n = 0; n < NN; ++n)
                    acc[m][n] = __builtin_amdgcn_mfma_f32_16x16x32_bf16(a[m], b[n], acc[m][n], 0, 0, 0);
        }
    }

    #pragma unroll
    for (int m = 0; m < 2; ++m) {
        #pragma unroll
        for (int n = 0; n < NN; ++n) {
            #pragma unroll
            for (int r = 0; r < 4; ++r) {
                int row = ra0 + wm * 32 + m * 16 + lh * 4 + r;
                int col = bn * BN + wn * (BN / 2) + n * 16 + l15;
                float v = acc[m][n][r];
                if constexpr (EPI == 1) {
                    fout[(size_t)row * 2048 + col] = v + bias[col];
                } else {
                    if (col < 2048) {
                        qb[(size_t)row * 2048 + col] = f2bf(v * 0.18033688011112042f);
                    } else if (col < 2560) {
                        int kcol = col - 2048, within = kcol & 63;
                        int cp = ((within >> 3) ^ (row & 7)) & 7;
                        kb[(size_t)row * 512 + (kcol & ~63) + (cp << 3) + (within & 7)] = f2bf(v);
                    } else {
                        int dg = col - 2560;
                        int cp = (((row >> 3) & 7) ^ (dg & 7)) & 7;
                        vt[(size_t)dg * 2048 + (row & ~63) + (cp << 3) + (row & 7)] = f2bf(v);
                    }
                }
            }
        }
    }
}

// ---------------------------------------------------------------------------
// Causal GQA attention: 8 waves = 4 q-strips {A0,A1,B0,B1} x kv-parity.
// (unchanged from round 5 except O-epilogue uses the 64-col GEMM-A swizzle)
__global__ __launch_bounds__(512, 4)
void attn_fwd(const short* __restrict__ qb, const short* __restrict__ kb,
              const short* __restrict__ vt, short* __restrict__ ob) {
    __shared__ __align__(16) short smem[2][16384];  // per buf: K 128x64 | V^T 64x128

    const int t = threadIdx.x, lane = t & 63, w = t >> 6;
    const int l31 = lane & 31, hi = lane >> 5;
    const int pairi = blockIdx.x;              // 0..15
    const int hq = blockIdx.y, hk = hq >> 2;
    const int qtA = pairi, qtB = 31 - pairi;
    const int a = w >> 1, p = w & 1;           // strip 0..3, kv parity
    const int myqt = (a < 2) ? qtA : qtB;
    const int q0 = myqt * 64 + (a & 1) * 32;
    const int rg = q0 + l31;                   // this lane's q row
    const int swl = l31 & 7;

    short8 qf[4];
    {
        const short* qrow = qb + (size_t)rg * 2048 + hq * 64;
        #pragma unroll
        for (int kk = 0; kk < 4; ++kk)
            qf[kk] = *(const short8*)(qrow + kk * 16 + hi * 8);
    }

    float m = -3e38f, l = 0.f;
    floatx16 acc[2] = {};

    auto stage = [&](int buf, int j0) {
        short* base = &smem[buf][0];
        #pragma unroll
        for (int i = 0; i < 4; ++i) {
            int c = i * 512 + t;
            if (i < 2) {                       // K chunks 0..1023
                int row = c >> 3, cc = c & 7;
                gload_lds16(kb + (size_t)(j0 + row) * 512 + hk * 64 + cc * 8, base + c * 8);
            } else {                           // V chunks 1024..2047
                int cv = c - 1024, drow = cv >> 4, cc = cv & 15;
                gload_lds16(vt + (size_t)(hk * 64 + drow) * 2048 + j0 + cc * 8, base + c * 8);
            }
        }
    };

    const int nss = (qtB >> 1) + 1;
    stage(0, 0);
    for (int ss = 0; ss < nss; ++ss) {
        __syncthreads();                       // slab ss ready
        if (ss + 1 < nss) stage((ss + 1) & 1, (ss + 1) * 128);
        const int kt = 2 * ss + p;
        if (kt <= myqt) {
            const short* K0 = &smem[ss & 1][0];
            const short* V0 = &smem[ss & 1][8192];

            // ---- S^T = K . Q^T
            floatx16 sT[2];
            #pragma unroll
            for (int kb2 = 0; kb2 < 2; ++kb2) {
                floatx16 acc2 = {};
                const int row = p * 64 + kb2 * 32 + l31;
                #pragma unroll
                for (int kk = 0; kk < 4; ++kk) {
                    short8 kf = *(const short8*)(K0 + row * 64 + (((2 * kk + hi) ^ swl) << 3));
                    acc2 = __builtin_amdgcn_mfma_f32_32x32x16_bf16(kf, qf[kk], acc2, 0, 0, 0);
                }
                sT[kb2] = acc2;
            }

            // ---- causal mask (diagonal tile only)
            if (kt == myqt) {
                #pragma unroll
                for (int kb2 = 0; kb2 < 2; ++kb2)
                    #pragma unroll
                    for (int r = 0; r < 16; ++r) {
                        int jg = kt * 64 + kb2 * 32 + (r & 3) + 8 * (r >> 2) + 4 * hi;
                        if (jg > rg) sT[kb2][r] = -3e38f;
                    }
            }

            // ---- row max
            float v[16];
            #pragma unroll
            for (int r = 0; r < 16; ++r) v[r] = fmaxf(sT[0][r], sT[1][r]);
            #pragma unroll
            for (int st = 8; st >= 1; st >>= 1)
                #pragma unroll
                for (int r = 0; r < 8; ++r)
                    if (r < st) v[r] = fmaxf(v[r], v[r + st]);
            float tm = fmaxf(v[0], __shfl_xor(v[0], 32));

            // ---- defer-max
            if (!__all(tm <= m + 8.0f)) {
                float mn = fmaxf(m, tm);
                float sf = __builtin_amdgcn_exp2f(m - mn);
                m = mn;
                l *= sf;
                #pragma unroll
                for (int n = 0; n < 2; ++n)
                    #pragma unroll
                    for (int r = 0; r < 16; ++r) acc[n][r] *= sf;
            }

            // ---- p = exp2(s - m), row sum
            float sv[16];
            #pragma unroll
            for (int kb2 = 0; kb2 < 2; ++kb2)
                #pragma unroll
                for (int r = 0; r < 16; ++r)
                    sT[kb2][r] = __builtin_amdgcn_exp2f(sT[kb2][r] - m);
            #pragma unroll
            for (int r = 0; r < 16; ++r) sv[r] = sT[0][r] + sT[1][r];
            #pragma unroll
            for (int st = 8; st >= 1; st >>= 1)
                #pragma unroll
                for (int r = 0; r < 8; ++r)
                    if (r < st) sv[r] += sv[r + st];
            l += sv[0] + __shfl_xor(sv[0], 32);

            // ---- P^T -> B-fragments, then PV
            #pragma unroll
            for (int kb2 = 0; kb2 < 2; ++kb2) {
                unsigned Qd[8], Pd[8];
                #pragma unroll
                for (int c = 0; c < 8; ++c)
                    Qd[c] = pk_bf16(sT[kb2][2 * c], sT[kb2][2 * c + 1]);
                #pragma unroll
                for (int c = 0; c < 8; ++c)
                    Pd[c] = __shfl_xor(Qd[c], 32);
                #pragma unroll
                for (int b = 0; b < 2; ++b) {
                    uintx4 j;
                    if (b == 0) {
                        j.x = hi ? Pd[2] : Qd[0];
                        j.y = hi ? Pd[3] : Qd[1];
                        j.z = hi ? Qd[2] : Pd[0];
                        j.w = hi ? Qd[3] : Pd[1];
                    } else {
                        j.x = hi ? Pd[6] : Qd[4];
                        j.y = hi ? Pd[7] : Qd[5];
                        j.z = hi ? Qd[6] : Pd[4];
                        j.w = hi ? Qd[7] : Pd[5];
                    }
                    short8 pf = __builtin_bit_cast(short8, j);
                    const int kk = kb2 * 2 + b;
                    const int ch = p * 64 + (((2 * kk + hi) ^ swl) << 3);
                    short8 vf0 = *(const short8*)(V0 + l31 * 128 + ch);
                    acc[0] = __builtin_amdgcn_mfma_f32_32x32x16_bf16(vf0, pf, acc[0], 0, 0, 0);
                    short8 vf1 = *(const short8*)(V0 + (32 + l31) * 128 + ch);
                    acc[1] = __builtin_amdgcn_mfma_f32_32x32x16_bf16(vf1, pf, acc[1], 0, 0, 0);
                }
            }
        }
    }

    // ---- merge the two kv-parity partials per strip (lane = q column)
    __syncthreads();
    float* mb = (float*)&smem[0][0] + ((size_t)a * 64 + lane) * 34;
    if (p == 1) {
        #pragma unroll
        for (int n = 0; n < 2; ++n)
            #pragma unroll
            for (int r = 0; r < 16; ++r) mb[n * 16 + r] = acc[n][r];
        mb[32] = m;
        mb[33] = l;
    }
    __syncthreads();
    if (p == 0) {
        const float m1 = mb[32], l1 = mb[33];
        const float M = fmaxf(m, m1);
        const float sf0 = __builtin_amdgcn_exp2f(m - M);
        const float sf1 = __builtin_amdgcn_exp2f(m1 - M);
        const float linv = 1.0f / (sf0 * l + sf1 * l1);
        const int sw8 = rg & 7;
        #pragma unroll
        for (int n = 0; n < 2; ++n) {
            #pragma unroll
            for (int g = 0; g < 4; ++g) {
                #pragma unroll
                for (int e = 0; e < 4; e += 2) {
                    int r = 4 * g + e;
                    float o0 = (sf0 * acc[n][r]     + sf1 * mb[n * 16 + r])     * linv;
                    float o1 = (sf0 * acc[n][r + 1] + sf1 * mb[n * 16 + r + 1]) * linv;
                    unsigned pkv = pk_bf16(o0, o1);
                    int d = 32 * n + e + 8 * g + 4 * hi;
                    int col = hq * 64 + d;
                    int cp = ((col >> 3) & 7) ^ sw8;           // 64-col GEMM-A swizzle
                    *(unsigned*)(ob + (size_t)rg * 2048 + (col & ~63) + (cp << 3) + (col & 7)) = pkv;
                }
            }
        }
    }
}

// ---------------------------------------------------------------------------
extern "C" void kernel_launch(void* const* d_in, const int* in_sizes, int n_in,
                              void* d_out, int out_size, void* d_ws, size_t ws_size,
                              hipStream_t stream) {
    const float* x  = (const float*)d_in[0];
    const float* Wq = (const float*)d_in[1];
    const float* Wk = (const float*)d_in[2];
    const float* Wv = (const float*)d_in[3];
    const float* Wo = (const float*)d_in[4];
    const float* bo = (const float*)d_in[5];

    char* ws = (char*)d_ws;
    short* xb   = (short*)ws;                            // 8 MiB (reused as ob)
    short* wqkv = (short*)(ws + ((size_t)8  << 20));     // 12 MiB (reused as wob)
    short* qb   = (short*)(ws + ((size_t)20 << 20));     // 8 MiB
    short* kb   = (short*)(ws + ((size_t)28 << 20));     // 2 MiB (attn-swizzled)
    short* vt   = (short*)(ws + ((size_t)30 << 20));     // 2 MiB (V^T, attn-swizzled)
    short* ob   = xb;      // x dead after QKV GEMM
    short* wob  = wqkv;    // qkv weights dead after QKV GEMM

    conv_all<<<5120, 256, 0, stream>>>(x, Wq, Wk, Wv, xb, wqkv);
    gemm8<128, 0><<<dim3(24, 16), 512, 0, stream>>>(xb, wqkv, qb, kb, vt, nullptr, nullptr);
    convsw<<<2048, 256, 0, stream>>>(Wo, wob);
    attn_fwd<<<dim3(16, 32), 512, 0, stream>>>(qb, kb, vt, ob);
    gemm8<64, 1><<<dim3(32, 16), 512, 0, stream>>>(ob, wob, nullptr, nullptr, nullptr,
                                                   (float*)d_out, bo);
}

// Round 8
// 122.050 us; speedup vs baseline: 1.4717x; 1.0025x over previous
//
#include <hip/hip_runtime.h>
#include <hip/hip_bf16.h>

typedef __attribute__((ext_vector_type(8))) short short8;
typedef __attribute__((ext_vector_type(16))) float floatx16;
typedef __attribute__((ext_vector_type(4))) float floatx4;
typedef __attribute__((ext_vector_type(4))) unsigned uintx4;

template<int N> struct IC { static constexpr int v = N; };

__device__ __forceinline__ short f2bf(float f) {
    unsigned u = __builtin_bit_cast(unsigned, f);
    u += 0x7fffu + ((u >> 16) & 1u);   // RNE
    return (short)(u >> 16);
}

__device__ __forceinline__ unsigned pk_bf16(float lo, float hi) {
    unsigned short a = __builtin_bit_cast(unsigned short, (__bf16)lo);
    unsigned short b = __builtin_bit_cast(unsigned short, (__bf16)hi);
    return (unsigned)a | ((unsigned)b << 16);
}

__device__ __forceinline__ void gload_lds16(const void* g, void* l) {
    __builtin_amdgcn_global_load_lds(
        (const __attribute__((address_space(1))) unsigned*)g,
        (__attribute__((address_space(3))) unsigned*)l, 16, 0, 0);
}

// ---------------------------------------------------------------------------
// f32 -> bf16 convert, 64-col-tile XOR swizzle (chunk cc <- cc ^ (row&7)).
__global__ __launch_bounds__(256)
void convsw(const float* __restrict__ src, short* __restrict__ dst) {
    const int row = blockIdx.x;
    const int c = threadIdx.x;
    const int kt = c >> 3, cc = c & 7;
    const float* s = src + (size_t)row * 2048 + kt * 64 + (cc ^ (row & 7)) * 8;
    float4 v0 = *(const float4*)s;
    float4 v1 = *(const float4*)(s + 4);
    short8 o = { f2bf(v0.x), f2bf(v0.y), f2bf(v0.z), f2bf(v0.w),
                 f2bf(v1.x), f2bf(v1.y), f2bf(v1.z), f2bf(v1.w) };
    *(short8*)(dst + (size_t)row * 2048 + kt * 64 + cc * 8) = o;
}

// x (2048 rows) -> xb, and Wq/Wk/Wv (3072 rows) -> wqkv, one launch.
__global__ __launch_bounds__(256)
void conv_all(const float* __restrict__ x, const float* __restrict__ Wq,
              const float* __restrict__ Wk, const float* __restrict__ Wv,
              short* __restrict__ xb, short* __restrict__ wqkv) {
    const int bid = blockIdx.x;                // 0..5119
    const float* src; short* dst; int srow, drow;
    if (bid < 2048)      { src = x;  dst = xb;   srow = bid;        drow = bid; }
    else {
        int r = bid - 2048;
        dst = wqkv; drow = r;
        if (r < 2048)      { src = Wq; srow = r; }
        else if (r < 2560) { src = Wk; srow = r - 2048; }
        else               { src = Wv; srow = r - 2560; }
    }
    const int c = threadIdx.x;
    const int kt = c >> 3, cc = c & 7;
    const float* s = src + (size_t)srow * 2048 + kt * 64 + (cc ^ (drow & 7)) * 8;
    float4 v0 = *(const float4*)s;
    float4 v1 = *(const float4*)(s + 4);
    short8 o = { f2bf(v0.x), f2bf(v0.y), f2bf(v0.z), f2bf(v0.w),
                 f2bf(v1.x), f2bf(v1.y), f2bf(v1.z), f2bf(v1.w) };
    *(short8*)(dst + (size_t)drow * 2048 + kt * 64 + cc * 8) = o;
}

// ---------------------------------------------------------------------------
// 8-wave double-buffered bf16 GEMM (unchanged from round 6).
template<int BN, int EPI>
__global__ __launch_bounds__(512, 4)
void gemm8(const short* __restrict__ A, const short* __restrict__ Bw,
           short* __restrict__ qb, short* __restrict__ kb, short* __restrict__ vt,
           float* __restrict__ fout, const float* __restrict__ bias) {
    constexpr int K = 2048;
    constexpr int NN = BN / 32;
    constexpr int ACH = 128 * 8;
    constexpr int NCH = (128 + BN) * 8;
    __shared__ short sm[2][(128 + BN) * 64];

    const int t = threadIdx.x, lane = t & 63, w = t >> 6;
    const int wm = w & 3, wn = w >> 2;
    const int l15 = lane & 15, lh = lane >> 4;
    const int bn = blockIdx.x, bm = blockIdx.y;
    const int ra0 = bm * 128;
    const short* Bbase = Bw + (size_t)bn * BN * K;

    floatx4 acc[2][NN] = {};

    auto stage = [&](int buf, int k0) {
        short* base = &sm[buf][0];
        #pragma unroll
        for (int i = 0; i < NCH / 512; ++i) {
            int c = i * 512 + t;
            if (c < ACH) {
                int row = c >> 3, cc = c & 7;
                gload_lds16(A + (size_t)(ra0 + row) * K + k0 + cc * 8, base + c * 8);
            } else {
                int c2 = c - ACH;
                int row = c2 >> 3, cc = c2 & 7;
                gload_lds16(Bbase + (size_t)row * K + k0 + cc * 8, base + (ACH + c2) * 8);
            }
        }
    };

    stage(0, 0);
    #pragma unroll 1
    for (int it = 0; it < K / 64; ++it) {
        __syncthreads();
        if (it + 1 < K / 64) stage((it + 1) & 1, (it + 1) * 64);
        const short* As = &sm[it & 1][0];
        const short* Bs = As + 128 * 64;
        #pragma unroll
        for (int kf = 0; kf < 2; ++kf) {
            short8 a[2], b[NN];
            #pragma unroll
            for (int m = 0; m < 2; ++m) {
                int arow = wm * 32 + m * 16 + l15;
                a[m] = *(const short8*)(As + arow * 64 + (((kf * 4 + lh) ^ (arow & 7)) << 3));
            }
            #pragma unroll
            for (int n = 0; n < NN; ++n) {
                int brow = wn * (BN / 2) + n * 16 + l15;
                b[n] = *(const short8*)(Bs + brow * 64 + (((kf * 4 + lh) ^ (brow & 7)) << 3));
            }
            #pragma unroll
            for (int m = 0; m < 2; ++m)
                #pragma unroll
                for (int n = 0; n < NN; ++n)
                    acc[m][n] = __builtin_amdgcn_mfma_f32_16x16x32_bf16(a[m], b[n], acc[m][n], 0, 0, 0);
        }
    }

    #pragma unroll
    for (int m = 0; m < 2; ++m) {
        #pragma unroll
        for (int n = 0; n < NN; ++n) {
            #pragma unroll
            for (int r = 0; r < 4; ++r) {
                int row = ra0 + wm * 32 + m * 16 + lh * 4 + r;
                int col = bn * BN + wn * (BN / 2) + n * 16 + l15;
                float v = acc[m][n][r];
                if constexpr (EPI == 1) {
                    fout[(size_t)row * 2048 + col] = v + bias[col];
                } else {
                    if (col < 2048) {
                        qb[(size_t)row * 2048 + col] = f2bf(v * 0.18033688011112042f);
                    } else if (col < 2560) {
                        int kcol = col - 2048, within = kcol & 63;
                        int cp = ((within >> 3) ^ (row & 7)) & 7;
                        kb[(size_t)row * 512 + (kcol & ~63) + (cp << 3) + (within & 7)] = f2bf(v);
                    } else {
                        int dg = col - 2560;
                        int cp = (((row >> 3) & 7) ^ (dg & 7)) & 7;
                        vt[(size_t)dg * 2048 + (row & ~63) + (cp << 3) + (row & 7)] = f2bf(v);
                    }
                }
            }
        }
    }
}

// ---------------------------------------------------------------------------
// Causal GQA attention, work-conserving phase-switch:
//  seg1 (ss < ss_tr): waves a<2 -> tile qtA (strip a, parity p, 64 kv rows),
//                     waves a>=2 -> tile qtB (strip a-2, parity p).
//  transition: A parity-partials merged via stale LDS slab, A written out;
//              A-waves reload Q for tile B and reset state.
//  seg2 (ss >= ss_tr): all 8 waves on tile B: (strip a&1, parity p, half a>>1),
//                      32 kv rows each. End: 4-way merge per strip via LDS.
__global__ __launch_bounds__(512, 4)
void attn_fwd(const short* __restrict__ qb, const short* __restrict__ kb,
              const short* __restrict__ vt, short* __restrict__ ob) {
    __shared__ __align__(16) short smem[2][16384];  // per buf: K 128x64 | V^T 64x128

    const int t = threadIdx.x, lane = t & 63, w = t >> 6;
    const int l31 = lane & 31, hi = lane >> 5;
    const int pairi = blockIdx.x;              // 0..15
    const int hq = blockIdx.y, hk = hq >> 2;
    const int qtA = pairi, qtB = 31 - pairi;
    const int a = w >> 1, p = w & 1;
    const int s = a & 1, h = a >> 1;           // strip, seg2 kv-half
    const int tile1 = (a < 2) ? qtA : qtB;
    const int swl = l31 & 7;

    int rg = tile1 * 64 + s * 32 + l31;        // this lane's current q row

    short8 qf[4];
    {
        const short* qrow = qb + (size_t)rg * 2048 + hq * 64;
        #pragma unroll
        for (int kk = 0; kk < 4; ++kk)
            qf[kk] = *(const short8*)(qrow + kk * 16 + hi * 8);
    }

    float m = -3e38f, l = 0.f;
    floatx16 acc[2] = {};

    auto stage = [&](int buf, int j0) {        // j0 = slab base kv-row (slab * 128)
        short* base = &smem[buf][0];
        #pragma unroll
        for (int i = 0; i < 4; ++i) {
            int c = i * 512 + t;
            if (i < 2) {
                int row = c >> 3, cc = c & 7;
                gload_lds16(kb + (size_t)(j0 + row) * 512 + hk * 64 + cc * 8, base + c * 8);
            } else {
                int cv = c - 1024, drow = cv >> 4, cc = cv & 15;
                gload_lds16(vt + (size_t)(hk * 64 + drow) * 2048 + j0 + cc * 8, base + c * 8);
            }
        }
    };

    auto save_part = [&](float* mb) {
        #pragma unroll
        for (int n = 0; n < 2; ++n)
            #pragma unroll
            for (int r = 0; r < 16; ++r) mb[n * 16 + r] = acc[n][r];
        mb[32] = m;
        mb[33] = l;
    };
    auto merge_part = [&](const float* mb) {
        float m1 = mb[32], l1 = mb[33];
        float M = fmaxf(m, m1);
        float sf0 = __builtin_amdgcn_exp2f(m - M);
        float sf1 = __builtin_amdgcn_exp2f(m1 - M);
        l = sf0 * l + sf1 * l1;
        #pragma unroll
        for (int n = 0; n < 2; ++n)
            #pragma unroll
            for (int r = 0; r < 16; ++r)
                acc[n][r] = sf0 * acc[n][r] + sf1 * mb[n * 16 + r];
        m = M;
    };
    auto writeout = [&](int rgw) {
        const float linv = 1.0f / l;
        const int sw8 = rgw & 7;
        #pragma unroll
        for (int n = 0; n < 2; ++n) {
            #pragma unroll
            for (int g = 0; g < 4; ++g) {
                #pragma unroll
                for (int e = 0; e < 4; e += 2) {
                    int r = 4 * g + e;
                    unsigned pkv = pk_bf16(acc[n][r] * linv, acc[n][r + 1] * linv);
                    int d = 32 * n + e + 8 * g + 4 * hi;
                    int col = hq * 64 + d;
                    int cp = ((col >> 3) & 7) ^ sw8;
                    *(unsigned*)(ob + (size_t)rgw * 2048 + (col & ~63) + (cp << 3) + (col & 7)) = pkv;
                }
            }
        }
    };

    auto process = [&](const short* K0, const short* V0, int blk0, auto NB,
                       int kt, bool diag) {
        constexpr int nblk = decltype(NB)::v;
        floatx16 sT[nblk];
        #pragma unroll
        for (int ib = 0; ib < nblk; ++ib) {
            floatx16 a2 = {};
            const int row = p * 64 + (blk0 + ib) * 32 + l31;
            #pragma unroll
            for (int kk = 0; kk < 4; ++kk) {
                short8 kf = *(const short8*)(K0 + row * 64 + (((2 * kk + hi) ^ swl) << 3));
                a2 = __builtin_amdgcn_mfma_f32_32x32x16_bf16(kf, qf[kk], a2, 0, 0, 0);
            }
            sT[ib] = a2;
        }
        if (diag) {
            #pragma unroll
            for (int ib = 0; ib < nblk; ++ib)
                #pragma unroll
                for (int r = 0; r < 16; ++r) {
                    int jg = kt * 64 + (blk0 + ib) * 32 + (r & 3) + 8 * (r >> 2) + 4 * hi;
                    if (jg > rg) sT[ib][r] = -3e38f;
                }
        }
        float v[16];
        #pragma unroll
        for (int r = 0; r < 16; ++r) {
            v[r] = sT[0][r];
            if constexpr (nblk == 2) v[r] = fmaxf(v[r], sT[1][r]);
        }
        #pragma unroll
        for (int st = 8; st >= 1; st >>= 1)
            #pragma unroll
            for (int r = 0; r < 8; ++r)
                if (r < st) v[r] = fmaxf(v[r], v[r + st]);
        float tm = fmaxf(v[0], __shfl_xor(v[0], 32));

        if (!__all(tm <= m + 8.0f)) {
            float mn = fmaxf(m, tm);
            float sf = __builtin_amdgcn_exp2f(m - mn);
            m = mn;
            l *= sf;
            #pragma unroll
            for (int n = 0; n < 2; ++n)
                #pragma unroll
                for (int r = 0; r < 16; ++r) acc[n][r] *= sf;
        }

        float sv[16];
        #pragma unroll
        for (int ib = 0; ib < nblk; ++ib)
            #pragma unroll
            for (int r = 0; r < 16; ++r)
                sT[ib][r] = __builtin_amdgcn_exp2f(sT[ib][r] - m);
        #pragma unroll
        for (int r = 0; r < 16; ++r) {
            sv[r] = sT[0][r];
            if constexpr (nblk == 2) sv[r] += sT[1][r];
        }
        #pragma unroll
        for (int st = 8; st >= 1; st >>= 1)
            #pragma unroll
            for (int r = 0; r < 8; ++r)
                if (r < st) sv[r] += sv[r + st];
        l += sv[0] + __shfl_xor(sv[0], 32);

        #pragma unroll
        for (int ib = 0; ib < nblk; ++ib) {
            unsigned Qd[8], Pd[8];
            #pragma unroll
            for (int c = 0; c < 8; ++c)
                Qd[c] = pk_bf16(sT[ib][2 * c], sT[ib][2 * c + 1]);
            #pragma unroll
            for (int c = 0; c < 8; ++c)
                Pd[c] = __shfl_xor(Qd[c], 32);
            #pragma unroll
            for (int b = 0; b < 2; ++b) {
                uintx4 j;
                if (b == 0) {
                    j.x = hi ? Pd[2] : Qd[0];
                    j.y = hi ? Pd[3] : Qd[1];
                    j.z = hi ? Qd[2] : Pd[0];
                    j.w = hi ? Qd[3] : Pd[1];
                } else {
                    j.x = hi ? Pd[6] : Qd[4];
                    j.y = hi ? Pd[7] : Qd[5];
                    j.z = hi ? Qd[6] : Pd[4];
                    j.w = hi ? Qd[7] : Pd[5];
                }
                short8 pf = __builtin_bit_cast(short8, j);
                const int kk = (blk0 + ib) * 2 + b;
                const int ch = p * 64 + (((2 * kk + hi) ^ swl) << 3);
                short8 vf0 = *(const short8*)(V0 + l31 * 128 + ch);
                acc[0] = __builtin_amdgcn_mfma_f32_32x32x16_bf16(vf0, pf, acc[0], 0, 0, 0);
                short8 vf1 = *(const short8*)(V0 + (32 + l31) * 128 + ch);
                acc[1] = __builtin_amdgcn_mfma_f32_32x32x16_bf16(vf1, pf, acc[1], 0, 0, 0);
            }
        }
    };

    const int ss_tr = (qtA >> 1) + 1;
    const int nss = (qtB >> 1) + 1;

    // ---- segment 1
    stage(0, 0);
    for (int ss = 0; ss < ss_tr; ++ss) {
        __syncthreads();                       // slab ss ready
        if (ss + 1 < ss_tr) stage((ss + 1) & 1, (ss + 1) * 128);
        const int kt = 2 * ss + p;
        if (kt <= tile1)
            process(&smem[ss & 1][0], &smem[ss & 1][8192], 0, IC<2>{}, kt, kt == tile1);
    }

    // ---- transition: A merge + writeout; all A-waves re-arm for tile B
    __syncthreads();                           // phase-1 compute done
    stage(ss_tr & 1, ss_tr * 128);             // prefetch seg2's first slab (fresh buf)
    {
        float* msc = (float*)&smem[(ss_tr - 1) & 1][0];
        if (a < 2 && p == 1) save_part(msc + (s * 64 + lane) * 34);
        __syncthreads();                       // partials visible
        if (a < 2 && p == 0) {
            merge_part(msc + (s * 64 + lane) * 34);
            writeout(rg);
        }
        if (a < 2) {
            rg = qtB * 64 + s * 32 + l31;
            const short* qrow = qb + (size_t)rg * 2048 + hq * 64;
            #pragma unroll
            for (int kk = 0; kk < 4; ++kk)
                qf[kk] = *(const short8*)(qrow + kk * 16 + hi * 8);
            m = -3e38f;
            l = 0.f;
            acc[0] = (floatx16){};
            acc[1] = (floatx16){};
        }
    }

    // ---- segment 2: all 8 waves on tile B, 32-kv-row sub-tiles
    for (int ss = ss_tr; ss < nss; ++ss) {
        __syncthreads();                       // slab ss ready; transition LDS reads done
        if (ss + 1 < nss) stage((ss + 1) & 1, (ss + 1) * 128);
        const int kt = 2 * ss + p;
        if (kt <= qtB)
            process(&smem[ss & 1][0], &smem[ss & 1][8192], h, IC<1>{}, kt, kt == qtB);
    }

    // ---- end: merge 4 partials per B strip (2 LDS steps)
    __syncthreads();
    float* msc = (float*)&smem[0][0];
    if (p == 1) save_part(msc + (a * 64 + lane) * 34);
    __syncthreads();
    if (p == 0) merge_part(msc + (a * 64 + lane) * 34);
    __syncthreads();
    if (p == 0 && a >= 2) save_part(msc + ((a & 1) * 64 + lane) * 34);
    __syncthreads();
    if (p == 0 && a < 2) {
        merge_part(msc + (a * 64 + lane) * 34);
        writeout(rg);
    }
}

// ---------------------------------------------------------------------------
extern "C" void kernel_launch(void* const* d_in, const int* in_sizes, int n_in,
                              void* d_out, int out_size, void* d_ws, size_t ws_size,
                              hipStream_t stream) {
    const float* x  = (const float*)d_in[0];
    const float* Wq = (const float*)d_in[1];
    const float* Wk = (const float*)d_in[2];
    const float* Wv = (const float*)d_in[3];
    const float* Wo = (const float*)d_in[4];
    const float* bo = (const float*)d_in[5];

    char* ws = (char*)d_ws;
    short* xb   = (short*)ws;                            // 8 MiB (reused as ob)
    short* wqkv = (short*)(ws + ((size_t)8  << 20));     // 12 MiB (reused as wob)
    short* qb   = (short*)(ws + ((size_t)20 << 20));     // 8 MiB
    short* kb   = (short*)(ws + ((size_t)28 << 20));     // 2 MiB (attn-swizzled)
    short* vt   = (short*)(ws + ((size_t)30 << 20));     // 2 MiB (V^T, attn-swizzled)
    short* ob   = xb;      // x dead after QKV GEMM
    short* wob  = wqkv;    // qkv weights dead after QKV GEMM

    conv_all<<<5120, 256, 0, stream>>>(x, Wq, Wk, Wv, xb, wqkv);
    gemm8<128, 0><<<dim3(24, 16), 512, 0, stream>>>(xb, wqkv, qb, kb, vt, nullptr, nullptr);
    convsw<<<2048, 256, 0, stream>>>(Wo, wob);
    attn_fwd<<<dim3(16, 32), 512, 0, stream>>>(qb, kb, vt, ob);
    gemm8<64, 1><<<dim3(32, 16), 512, 0, stream>>>(ob, wob, nullptr, nullptr, nullptr,
                                                   (float*)d_out, bo);
}